// Round 2
// baseline (5652.389 us; speedup 1.0000x reference)
//
#include <hip/hip_runtime.h>
#include <hip/hip_bf16.h>

// ---------------------------------------------------------------------------
// NaViT-ROPE forward, fp32. B=4, N=1024, C=384, H=6, HD=64, DEPTH=12.
// Round 2: fix rope_kernel overrun (p<576 -> p<384). Otherwise identical.
// ---------------------------------------------------------------------------

#define EMBED 384
#define NHEADS 6
#define HD 64
#define NSEQ 1024
#define NB 4
#define NROWS (NB * NSEQ)          // 4096
#define PD 96                      // 3*8*4 patch dim

__constant__ int c_lens[4] = {512, 768, 896, 1024};

// ---------------------------------------------------------------- patchify
__global__ void patchify_kernel(const float* __restrict__ i0, const float* __restrict__ i1,
                                const float* __restrict__ i2, const float* __restrict__ i3,
                                float* __restrict__ xin, float* __restrict__ cosT,
                                float* __restrict__ sinT) {
    int bn = blockIdx.x;               // 0..4095
    int b = bn >> 10, n = bn & 1023;
    const int lens[4] = {512, 768, 896, 1024};
    const int pws[4]  = {128, 192, 224, 256};
    const float* imgs[4] = {i0, i1, i2, i3};
    int len = lens[b], pw = pws[b];
    int W = pw * 4;
    int t = threadIdx.x;               // 128
    float* xrow = xin + (size_t)bn * PD;
    if (n < len) {
        int pr = n / pw, pc = n - pr * pw;       // ty, tx
        const float* img = imgs[b];
        if (t < PD) {
            int c = t >> 5, py = (t >> 2) & 7, px = t & 3;
            xrow[t] = img[(size_t)c * 32 * W + (size_t)(pr * 8 + py) * W + pc * 4 + px];
        }
        if (t < 32) {
            int j = t & 15;
            float fr = powf(100.0f, -(float)j / 16.0f);
            float coord = (t < 16) ? (float)pc : (float)pr;
            float ang = coord * fr;
            cosT[(size_t)bn * 32 + t] = cosf(ang);
            sinT[(size_t)bn * 32 + t] = sinf(ang);
        }
    } else {
        if (t < PD) xrow[t] = 0.f;
        if (t < 32) { cosT[(size_t)bn * 32 + t] = 0.f; sinT[(size_t)bn * 32 + t] = 0.f; }
    }
}

// ---------------------------------------------------------------- layernorm
template <int C>
__global__ void ln_kernel(const float* __restrict__ in, const float* __restrict__ w,
                          const float* __restrict__ bias, float* __restrict__ out) {
    int row = blockIdx.x;
    const float* x = in + (size_t)row * C;
    float* y = out + (size_t)row * C;
    int t = threadIdx.x;  // 64
    constexpr int NE = (C + 63) / 64;
    float vals[NE];
    float s = 0.f;
#pragma unroll
    for (int i = 0; i < NE; i++) {
        int e = t + i * 64;
        float v = (e < C) ? x[e] : 0.f;
        vals[i] = v;
        s += v;
    }
#pragma unroll
    for (int off = 32; off; off >>= 1) s += __shfl_down(s, off);
    float mean = __shfl(s, 0) / (float)C;
    float vs = 0.f;
#pragma unroll
    for (int i = 0; i < NE; i++) {
        int e = t + i * 64;
        float d = (e < C) ? (vals[i] - mean) : 0.f;
        vs += d * d;
    }
#pragma unroll
    for (int off = 32; off; off >>= 1) vs += __shfl_down(vs, off);
    float rstd = rsqrtf(__shfl(vs, 0) / (float)C + 1e-5f);
#pragma unroll
    for (int i = 0; i < NE; i++) {
        int e = t + i * 64;
        if (e < C) y[e] = (vals[i] - mean) * rstd * w[e] + bias[e];
    }
}

// ---------------------------------------------------------------- GEMM
// C[M,N] = A[M,K] @ W[K,N]  (+bias +gelu +residual per FLAGS)
// FLAGS: 1=bias, 2=gelu(exact erf), 4=residual add
#define BM 64
#define BN 64
#define BK 16

template <int FLAGS>
__global__ __launch_bounds__(256) void gemm_kernel(
    const float* __restrict__ A, const float* __restrict__ W,
    const float* __restrict__ bias, const float* __restrict__ res,
    float* __restrict__ out, int M, int K, int N) {
    __shared__ __align__(16) float As[BK][68];  // transposed A tile, padded
    __shared__ __align__(16) float Bs[BK][BN];
    int bx = blockIdx.x, by = blockIdx.y;
    int t = threadIdx.x;
    int tx = t & 15, ty = t >> 4;
    float acc[4][4] = {};
    int arow = t >> 2;           // 0..63
    int acol4 = (t & 3) * 4;     // 0,4,8,12
    int brow = t >> 4;           // 0..15
    int bcol4 = (t & 15) * 4;
    const float* Ab = A + (size_t)(by * BM) * K;
    const float* Wb = W + bx * BN;
    for (int k0 = 0; k0 < K; k0 += BK) {
        float4 av = *(const float4*)(Ab + (size_t)arow * K + k0 + acol4);
        As[acol4 + 0][arow] = av.x;
        As[acol4 + 1][arow] = av.y;
        As[acol4 + 2][arow] = av.z;
        As[acol4 + 3][arow] = av.w;
        *(float4*)&Bs[brow][bcol4] =
            *(const float4*)(Wb + (size_t)(k0 + brow) * N + bcol4);
        __syncthreads();
#pragma unroll
        for (int kk = 0; kk < BK; kk++) {
            float4 a = *(const float4*)&As[kk][ty * 4];
            float4 bvv = *(const float4*)&Bs[kk][tx * 4];
            float af[4] = {a.x, a.y, a.z, a.w};
            float bf[4] = {bvv.x, bvv.y, bvv.z, bvv.w};
#pragma unroll
            for (int i = 0; i < 4; i++)
#pragma unroll
                for (int j = 0; j < 4; j++) acc[i][j] += af[i] * bf[j];
        }
        __syncthreads();
    }
    int orow = by * BM + ty * 4;
    int ocol = bx * BN + tx * 4;
#pragma unroll
    for (int i = 0; i < 4; i++) {
        float v[4];
#pragma unroll
        for (int j = 0; j < 4; j++) {
            float x = acc[i][j];
            if (FLAGS & 1) x += bias[ocol + j];
            if (FLAGS & 2) x = 0.5f * x * (1.f + erff(x * 0.70710678118654752f));
            if (FLAGS & 4) x += res[(size_t)(orow + i) * N + ocol + j];
            v[j] = x;
        }
        *(float4*)(out + (size_t)(orow + i) * N + ocol) =
            make_float4(v[0], v[1], v[2], v[3]);
    }
}

// ---------------------------------------------------------------- rope + rearrange
// qkv (B,N,1152) -> qr/kr/vr (B*H, N, 64); rope on q,k; q scaled by HD^-0.5
__global__ void rope_kernel(const float* __restrict__ qkv, const float* __restrict__ cosT,
                            const float* __restrict__ sinT, float* __restrict__ qr,
                            float* __restrict__ kr, float* __restrict__ vr) {
    int bn = blockIdx.x;
    int b = bn >> 10, n = bn & 1023;
    const float* row = qkv + (size_t)bn * 1152;
    const float* cs = cosT + (size_t)bn * 32;
    const float* sn = sinT + (size_t)bn * 32;
    int t = threadIdx.x;  // 256
    const float scale = 0.125f;
    // 192 q pairs + 192 k pairs = 384 rope pairs total
    for (int p = t; p < 384; p += 256) {
        int isK = (p >= 192) ? 1 : 0;
        int pq = p - isK * 192;
        int hh = pq >> 5, pp = pq & 31;
        int base = isK * 384 + hh * 64 + 2 * pp;
        float x0 = row[base], x1 = row[base + 1];
        float c = cs[pp], s = sn[pp];
        float o0 = x0 * c - x1 * s;
        float o1 = x0 * s + x1 * c;
        float m = isK ? 1.0f : scale;
        float* dst = (isK ? kr : qr) + ((size_t)(b * NHEADS + hh) * NSEQ + n) * HD + 2 * pp;
        dst[0] = o0 * m;
        dst[1] = o1 * m;
    }
    for (int e = t; e < 384; e += 256) {
        int hh = e >> 6, d = e & 63;
        vr[((size_t)(b * NHEADS + hh) * NSEQ + n) * HD + d] = row[768 + e];
    }
}

// ---------------------------------------------------------------- attention (flash-style)
// grid (24, 16): (b*6+h, q-tile of 64). 256 threads.
// thread (qg=t>>4, kg=t&15): S rows 4qg+i, S cols kg+16j; O rows 4qg+i, O cols 4kg+dd.
__global__ __launch_bounds__(256) void attn_kernel(const float* __restrict__ qr,
                                                   const float* __restrict__ kr,
                                                   const float* __restrict__ vr,
                                                   float* __restrict__ o) {
    constexpr int PS = 76;  // pad: 76*4B % 16 == 0 (float4 ok), stride mod 32 = 12 (2-way max)
    __shared__ __align__(16) float Qs[64][PS];
    __shared__ __align__(16) float Ks[64][PS];
    __shared__ __align__(16) float Vs[64][PS];
    __shared__ __align__(16) float Ss[64][PS];
    int bh = blockIdx.x;
    int b = bh / 6, hh = bh - b * 6;
    int q0 = blockIdx.y * 64;
    int len = c_lens[b];
    int t = threadIdx.x;
    int qg = t >> 4;   // 0..15
    int kg = t & 15;   // 0..15
    const float* Qb = qr + ((size_t)bh * NSEQ + q0) * HD;
    const float* Kb = kr + (size_t)bh * NSEQ * HD;
    const float* Vb = vr + (size_t)bh * NSEQ * HD;
    {
        int r = t >> 2, db = (t & 3) * 16;
#pragma unroll
        for (int c = 0; c < 16; c += 4)
            *(float4*)&Qs[r][db + c] = *(const float4*)(Qb + (size_t)r * HD + db + c);
    }
    float m_r[4], l_r[4];
#pragma unroll
    for (int i = 0; i < 4; i++) { m_r[i] = -1e30f; l_r[i] = 0.f; }
    float oacc[4][4] = {};

    for (int k0 = 0; k0 < NSEQ; k0 += 64) {
        __syncthreads();  // prev PV done before overwriting Ks/Vs (also covers Q load)
        {
            int r = t >> 2, db = (t & 3) * 16;
            const float* kp = Kb + (size_t)(k0 + r) * HD + db;
            const float* vp = Vb + (size_t)(k0 + r) * HD + db;
#pragma unroll
            for (int c = 0; c < 16; c += 4) {
                *(float4*)&Ks[r][db + c] = *(const float4*)(kp + c);
                *(float4*)&Vs[r][db + c] = *(const float4*)(vp + c);
            }
        }
        __syncthreads();
        // S = (q*scale) @ k^T  -- scale already folded into q
        float sacc[4][4] = {};
#pragma unroll 4
        for (int d = 0; d < HD; d += 4) {
            float4 qv[4], kv[4];
#pragma unroll
            for (int i = 0; i < 4; i++) qv[i] = *(const float4*)&Qs[4 * qg + i][d];
#pragma unroll
            for (int j = 0; j < 4; j++) kv[j] = *(const float4*)&Ks[kg + 16 * j][d];
#pragma unroll
            for (int i = 0; i < 4; i++)
#pragma unroll
                for (int j = 0; j < 4; j++)
                    sacc[i][j] += qv[i].x * kv[j].x + qv[i].y * kv[j].y +
                                  qv[i].z * kv[j].z + qv[i].w * kv[j].w;
        }
        // online softmax (row state in registers; 16-lane row groups)
        float al[4];
#pragma unroll
        for (int i = 0; i < 4; i++) {
            float mx = -1e30f;
#pragma unroll
            for (int j = 0; j < 4; j++) {
                bool valid = (k0 + kg + 16 * j) < len;
                sacc[i][j] = valid ? sacc[i][j] : -1e30f;
                mx = fmaxf(mx, sacc[i][j]);
            }
            mx = fmaxf(mx, __shfl_xor(mx, 1));
            mx = fmaxf(mx, __shfl_xor(mx, 2));
            mx = fmaxf(mx, __shfl_xor(mx, 4));
            mx = fmaxf(mx, __shfl_xor(mx, 8));
            float newm = fmaxf(m_r[i], mx);
            al[i] = __expf(m_r[i] - newm);
            float sum = 0.f;
#pragma unroll
            for (int j = 0; j < 4; j++) {
                float e = (sacc[i][j] > -1e29f) ? __expf(sacc[i][j] - newm) : 0.f;
                sacc[i][j] = e;
                sum += e;
            }
            sum += __shfl_xor(sum, 1);
            sum += __shfl_xor(sum, 2);
            sum += __shfl_xor(sum, 4);
            sum += __shfl_xor(sum, 8);
            l_r[i] = l_r[i] * al[i] + sum;
            m_r[i] = newm;
#pragma unroll
            for (int j = 0; j < 4; j++) Ss[4 * qg + i][kg + 16 * j] = sacc[i][j];
        }
        __syncthreads();
        // O = O*alpha + P @ V
#pragma unroll
        for (int i = 0; i < 4; i++)
#pragma unroll
            for (int dd = 0; dd < 4; dd++) oacc[i][dd] *= al[i];
        for (int kj = 0; kj < 64; kj += 4) {
            float4 sv[4], vv[4];
#pragma unroll
            for (int i = 0; i < 4; i++) sv[i] = *(const float4*)&Ss[4 * qg + i][kj];
#pragma unroll
            for (int j = 0; j < 4; j++) vv[j] = *(const float4*)&Vs[kj + j][4 * kg];
#pragma unroll
            for (int i = 0; i < 4; i++) {
                oacc[i][0] += sv[i].x * vv[0].x + sv[i].y * vv[1].x + sv[i].z * vv[2].x + sv[i].w * vv[3].x;
                oacc[i][1] += sv[i].x * vv[0].y + sv[i].y * vv[1].y + sv[i].z * vv[2].y + sv[i].w * vv[3].y;
                oacc[i][2] += sv[i].x * vv[0].z + sv[i].y * vv[1].z + sv[i].z * vv[2].z + sv[i].w * vv[3].z;
                oacc[i][3] += sv[i].x * vv[0].w + sv[i].y * vv[1].w + sv[i].z * vv[2].w + sv[i].w * vv[3].w;
            }
        }
    }
#pragma unroll
    for (int i = 0; i < 4; i++) {
        float inv = 1.f / l_r[i];
        int row = q0 + 4 * qg + i;
        float* po = o + ((size_t)(b * NSEQ) + row) * EMBED + hh * HD + 4 * kg;
        *(float4*)po = make_float4(oacc[i][0] * inv, oacc[i][1] * inv,
                                   oacc[i][2] * inv, oacc[i][3] * inv);
    }
}

// ---------------------------------------------------------------- mask output
__global__ void mask_kernel(float* __restrict__ mout) {
    int idx = blockIdx.x * 256 + threadIdx.x;
    if (idx >= NROWS) return;
    int b = idx >> 10, n = idx & 1023;
    mout[idx] = (n >= c_lens[b]) ? 1.0f : 0.0f;
}

// ---------------------------------------------------------------- launch
extern "C" void kernel_launch(void* const* d_in, const int* in_sizes, int n_in,
                              void* d_out, int out_size, void* d_ws, size_t ws_size,
                              hipStream_t stream) {
    (void)in_sizes; (void)n_in; (void)out_size; (void)ws_size;
    const float* img0 = (const float*)d_in[0];
    const float* img1 = (const float*)d_in[1];
    const float* img2 = (const float*)d_in[2];
    const float* img3 = (const float*)d_in[3];
    const float* pe_ln_in_w  = (const float*)d_in[4];
    const float* pe_ln_in_b  = (const float*)d_in[5];
    const float* pe_w        = (const float*)d_in[6];
    const float* pe_ln_out_w = (const float*)d_in[7];
    const float* pe_ln_out_b = (const float*)d_in[8];
    const float* ln1_w  = (const float*)d_in[9];
    const float* ln1_b  = (const float*)d_in[10];
    const float* qkv_w  = (const float*)d_in[11];
    const float* qkv_b  = (const float*)d_in[12];
    const float* proj_w = (const float*)d_in[13];
    const float* proj_b = (const float*)d_in[14];
    const float* ln2_w  = (const float*)d_in[15];
    const float* ln2_b  = (const float*)d_in[16];
    const float* fc1_w  = (const float*)d_in[17];
    const float* fc1_b  = (const float*)d_in[18];
    const float* fc2_w  = (const float*)d_in[19];
    const float* fc2_b  = (const float*)d_in[20];
    const float* lnf_w  = (const float*)d_in[21];
    const float* lnf_b  = (const float*)d_in[22];

    float* ws = (float*)d_ws;
    float* x    = ws;                    // 1,572,864
    float* h    = ws + 1572864;          // 1,572,864
    float* qkv  = ws + 3145728;          // 4,718,592
    float* qr   = ws + 7864320;          // 1,572,864
    float* kr   = ws + 9437184;          // 1,572,864
    float* vr   = ws + 11010048;         // 1,572,864
    float* o    = qkv;                   // reuse (qkv dead after rope)
    float* mlp  = qkv;                   // reuse qkv+qr (both dead during MLP)
    float* xin  = ws + 12582912;         // 393,216
    float* xln  = ws + 12976128;         // 393,216
    float* cosT = ws + 13369344;         // 131,072
    float* sinT = ws + 13500416;         // 131,072  -> total 13,631,488 f = 54.5 MB

    patchify_kernel<<<NROWS, 128, 0, stream>>>(img0, img1, img2, img3, xin, cosT, sinT);
    ln_kernel<PD><<<NROWS, 64, 0, stream>>>(xin, pe_ln_in_w, pe_ln_in_b, xln);
    gemm_kernel<0><<<dim3(EMBED / BN, NROWS / BM), 256, 0, stream>>>(
        xln, pe_w, nullptr, nullptr, x, NROWS, PD, EMBED);
    ln_kernel<EMBED><<<NROWS, 64, 0, stream>>>(x, pe_ln_out_w, pe_ln_out_b, x);

    for (int l = 0; l < 12; ++l) {
        ln_kernel<EMBED><<<NROWS, 64, 0, stream>>>(x, ln1_w + l * EMBED, ln1_b + l * EMBED, h);
        gemm_kernel<1><<<dim3(1152 / BN, NROWS / BM), 256, 0, stream>>>(
            h, qkv_w + (size_t)l * EMBED * 1152, qkv_b + (size_t)l * 1152, nullptr,
            qkv, NROWS, EMBED, 1152);
        rope_kernel<<<NROWS, 256, 0, stream>>>(qkv, cosT, sinT, qr, kr, vr);
        attn_kernel<<<dim3(NB * NHEADS, NSEQ / 64), 256, 0, stream>>>(qr, kr, vr, o);
        gemm_kernel<5><<<dim3(EMBED / BN, NROWS / BM), 256, 0, stream>>>(
            o, proj_w + (size_t)l * EMBED * EMBED, proj_b + (size_t)l * EMBED, x,
            x, NROWS, EMBED, EMBED);
        ln_kernel<EMBED><<<NROWS, 64, 0, stream>>>(x, ln2_w + l * EMBED, ln2_b + l * EMBED, h);
        gemm_kernel<3><<<dim3(1536 / BN, NROWS / BM), 256, 0, stream>>>(
            h, fc1_w + (size_t)l * EMBED * 1536, fc1_b + (size_t)l * 1536, nullptr,
            mlp, NROWS, EMBED, 1536);
        gemm_kernel<5><<<dim3(EMBED / BN, NROWS / BM), 256, 0, stream>>>(
            mlp, fc2_w + (size_t)l * 1536 * EMBED, fc2_b + (size_t)l * EMBED, x,
            x, NROWS, 1536, EMBED);
    }

    ln_kernel<EMBED><<<NROWS, 64, 0, stream>>>(x, lnf_w, lnf_b, (float*)d_out);
    mask_kernel<<<16, 256, 0, stream>>>((float*)d_out + (size_t)NROWS * EMBED);
}

// Round 3
// 1665.094 us; speedup vs baseline: 3.3946x; 3.3946x over previous
//
#include <hip/hip_runtime.h>

// ---------------------------------------------------------------------------
// NaViT-ROPE forward. Round 3: bf16 MFMA GEMMs + MFMA flash attention.
// B=4, N=1024, C=384, H=6, HD=64, DEPTH=12.  gfx950 mfma_f32_16x16x32_bf16.
// Fragment layouts (m89-verified): A: lane holds A[l&15][(l>>4)*8+i];
// B: B[(l>>4)*8+i][l&15]; D: row=(l>>4)*4+r, col=l&15.
// ---------------------------------------------------------------------------

#define EMBED 384
#define NHEADS 6
#define HD 64
#define NSEQ 1024
#define NB 4
#define NROWS (NB * NSEQ)          // 4096
#define PD 96

typedef __attribute__((ext_vector_type(8))) short bf16x8;
typedef __attribute__((ext_vector_type(4))) float f32x4;

__constant__ int c_lens[4] = {512, 768, 896, 1024};

__device__ __forceinline__ unsigned f2bf(float f) {   // RNE f32->bf16 bits
    unsigned u = __float_as_uint(f);
    return (u + 0x7fffu + ((u >> 16) & 1u)) >> 16;
}
__device__ __forceinline__ float bf2f(unsigned short h) {
    return __uint_as_float(((unsigned)h) << 16);
}

// ---------------------------------------------------------------- patchify (unchanged)
__global__ void patchify_kernel(const float* __restrict__ i0, const float* __restrict__ i1,
                                const float* __restrict__ i2, const float* __restrict__ i3,
                                float* __restrict__ xin, float* __restrict__ cosT,
                                float* __restrict__ sinT) {
    int bn = blockIdx.x;
    int b = bn >> 10, n = bn & 1023;
    const int lens[4] = {512, 768, 896, 1024};
    const int pws[4]  = {128, 192, 224, 256};
    const float* imgs[4] = {i0, i1, i2, i3};
    int len = lens[b], pw = pws[b];
    int W = pw * 4;
    int t = threadIdx.x;               // 128
    float* xrow = xin + (size_t)bn * PD;
    if (n < len) {
        int pr = n / pw, pc = n - pr * pw;
        const float* img = imgs[b];
        if (t < PD) {
            int c = t >> 5, py = (t >> 2) & 7, px = t & 3;
            xrow[t] = img[(size_t)c * 32 * W + (size_t)(pr * 8 + py) * W + pc * 4 + px];
        }
        if (t < 32) {
            int j = t & 15;
            float fr = powf(100.0f, -(float)j / 16.0f);
            float coord = (t < 16) ? (float)pc : (float)pr;
            float ang = coord * fr;
            cosT[(size_t)bn * 32 + t] = cosf(ang);
            sinT[(size_t)bn * 32 + t] = sinf(ang);
        }
    } else {
        if (t < PD) xrow[t] = 0.f;
        if (t < 32) { cosT[(size_t)bn * 32 + t] = 0.f; sinT[(size_t)bn * 32 + t] = 0.f; }
    }
}

// ---------------------------------------------------------------- weight transpose+convert
// src f32 [L][K][N] -> dst bf16 [L][N][Kpad], zero-filled for k in [K,Kpad)
__global__ void convT_kernel(const float* __restrict__ src, unsigned short* __restrict__ dst,
                             int K, int N, int Kpad) {
    __shared__ float tile[32][33];
    int k0 = blockIdx.x * 32, n0 = blockIdx.y * 32, l = blockIdx.z;
    int t = threadIdx.x;               // 256
    {
        int kk = t >> 3, nn = (t & 7) * 4;
        float4 v = make_float4(0.f, 0.f, 0.f, 0.f);
        if (k0 + kk < K)
            v = *(const float4*)(src + ((size_t)l * K + (k0 + kk)) * N + n0 + nn);
        tile[kk][nn + 0] = v.x; tile[kk][nn + 1] = v.y;
        tile[kk][nn + 2] = v.z; tile[kk][nn + 3] = v.w;
    }
    __syncthreads();
    {
        int nn = t >> 3, kk = (t & 7) * 4;
        unsigned lo = f2bf(tile[kk + 0][nn]) | (f2bf(tile[kk + 1][nn]) << 16);
        unsigned hi = f2bf(tile[kk + 2][nn]) | (f2bf(tile[kk + 3][nn]) << 16);
        uint2 u = make_uint2(lo, hi);
        *(uint2*)(dst + (size_t)l * N * Kpad + (size_t)(n0 + nn) * Kpad + k0 + kk) = u;
    }
}

// ---------------------------------------------------------------- layernorm (wave per row)
// OBF: write bf16 (output stride OS, zero-fill cols C..OS). else f32 (stride OS==C).
template <int C, int OS, bool OBF>
__global__ void ln_kernel(const float* __restrict__ in, const float* __restrict__ w,
                          const float* __restrict__ bias, void* __restrict__ outv) {
    int row = blockIdx.x * 4 + (threadIdx.x >> 6);
    int t = threadIdx.x & 63;
    const float* x = in + (size_t)row * C;
    constexpr int NE = (C + 63) / 64;
    float vals[NE];
    float s = 0.f;
#pragma unroll
    for (int i = 0; i < NE; i++) {
        int e = t + i * 64;
        float v = (e < C) ? x[e] : 0.f;
        vals[i] = v; s += v;
    }
#pragma unroll
    for (int off = 32; off; off >>= 1) s += __shfl_down(s, off);
    float mean = __shfl(s, 0) / (float)C;
    float vs = 0.f;
#pragma unroll
    for (int i = 0; i < NE; i++) {
        int e = t + i * 64;
        float d = (e < C) ? (vals[i] - mean) : 0.f;
        vs += d * d;
    }
#pragma unroll
    for (int off = 32; off; off >>= 1) vs += __shfl_down(vs, off);
    float rstd = rsqrtf(__shfl(vs, 0) / (float)C + 1e-5f);
    constexpr int NO = (OS + 63) / 64;
#pragma unroll
    for (int i = 0; i < NO; i++) {
        int e = t + i * 64;
        if (e < OS) {
            float v = (e < C) ? ((vals[i] - mean) * rstd * w[e] + bias[e]) : 0.f;
            if (OBF) ((unsigned short*)outv)[(size_t)row * OS + e] = (unsigned short)f2bf(v);
            else     ((float*)outv)[(size_t)row * OS + e] = v;
        }
    }
}

// ---------------------------------------------------------------- bf16 MFMA GEMM
// out[M,N] = A[M,K](bf16) @ Wt[N,K](bf16, pre-transposed) (+bias +gelu +res per FLAGS)
// FLAGS: 1=bias, 2=gelu, 4=residual(f32), 8=bf16 output (else f32)
template <int FLAGS>
__global__ __launch_bounds__(256) void gemm_bf16(
    const unsigned short* __restrict__ A, const unsigned short* __restrict__ Wt,
    const float* __restrict__ bias, const float* __restrict__ res,
    float* __restrict__ outf, unsigned short* __restrict__ outb,
    int M, int K, int N) {
    __shared__ unsigned short As[64][72];   // stride 144B: banks 4r%32 -> 2-way (free)
    __shared__ unsigned short Bs[64][72];
    int t = threadIdx.x;
    int wid = t >> 6, lane = t & 63;
    int m0 = blockIdx.y * 64, n0 = blockIdx.x * 64;
    int wm = (wid >> 1) * 32, wn = (wid & 1) * 32;
    f32x4 acc[2][2] = {};
    int srow = t >> 2, sc = (t & 3) * 8;
    const unsigned short* Ap = A + (size_t)(m0 + srow) * K + sc;
    const unsigned short* Bp = Wt + (size_t)(n0 + srow) * K + sc;
    int lr = lane & 15, lk = (lane >> 4) * 8;
    for (int k0 = 0; k0 < K; k0 += 64) {
        *(uint4*)&As[srow][sc]      = *(const uint4*)(Ap + k0);
        *(uint4*)&As[srow][sc + 32] = *(const uint4*)(Ap + k0 + 32);
        *(uint4*)&Bs[srow][sc]      = *(const uint4*)(Bp + k0);
        *(uint4*)&Bs[srow][sc + 32] = *(const uint4*)(Bp + k0 + 32);
        __syncthreads();
#pragma unroll
        for (int kk = 0; kk < 64; kk += 32) {
            bf16x8 a0 = *(const bf16x8*)&As[wm + lr][kk + lk];
            bf16x8 a1 = *(const bf16x8*)&As[wm + 16 + lr][kk + lk];
            bf16x8 b0 = *(const bf16x8*)&Bs[wn + lr][kk + lk];
            bf16x8 b1 = *(const bf16x8*)&Bs[wn + 16 + lr][kk + lk];
            acc[0][0] = __builtin_amdgcn_mfma_f32_16x16x32_bf16(a0, b0, acc[0][0], 0, 0, 0);
            acc[0][1] = __builtin_amdgcn_mfma_f32_16x16x32_bf16(a0, b1, acc[0][1], 0, 0, 0);
            acc[1][0] = __builtin_amdgcn_mfma_f32_16x16x32_bf16(a1, b0, acc[1][0], 0, 0, 0);
            acc[1][1] = __builtin_amdgcn_mfma_f32_16x16x32_bf16(a1, b1, acc[1][1], 0, 0, 0);
        }
        __syncthreads();
    }
    int lq = lane >> 4;
#pragma unroll
    for (int mi = 0; mi < 2; mi++)
#pragma unroll
        for (int ni = 0; ni < 2; ni++) {
#pragma unroll
            for (int r = 0; r < 4; r++) {
                int grow = m0 + wm + mi * 16 + lq * 4 + r;
                int gcol = n0 + wn + ni * 16 + lr;
                float v = acc[mi][ni][r];
                if (FLAGS & 1) v += bias[gcol];
                if (FLAGS & 2) v = 0.5f * v * (1.f + erff(v * 0.70710678118654752f));
                if (FLAGS & 4) v += res[(size_t)grow * N + gcol];
                if (FLAGS & 8) outb[(size_t)grow * N + gcol] = (unsigned short)f2bf(v);
                else           outf[(size_t)grow * N + gcol] = v;
            }
        }
}

// ---------------------------------------------------------------- rope + rearrange (bf16)
// qkv bf16 [4096][1152] -> qr,kr bf16 [24][1024][64]; vt bf16 [24][64][1024] (transposed)
__global__ void rope_kernel(const unsigned short* __restrict__ qkv,
                            const float* __restrict__ cosT, const float* __restrict__ sinT,
                            unsigned short* __restrict__ qr, unsigned short* __restrict__ kr,
                            unsigned short* __restrict__ vt) {
    int bn = blockIdx.x;
    int b = bn >> 10, n = bn & 1023;
    const unsigned short* row = qkv + (size_t)bn * 1152;
    const float* cs = cosT + (size_t)bn * 32;
    const float* sn = sinT + (size_t)bn * 32;
    int t = threadIdx.x;  // 256
    for (int p = t; p < 384; p += 256) {
        int isK = (p >= 192) ? 1 : 0;
        int pq = p - isK * 192;
        int hh = pq >> 5, pp = pq & 31;
        int base = isK * 384 + hh * 64 + 2 * pp;
        float x0 = bf2f(row[base]), x1 = bf2f(row[base + 1]);
        float c = cs[pp], s = sn[pp];
        float o0 = x0 * c - x1 * s;
        float o1 = x0 * s + x1 * c;
        float m = isK ? 1.0f : 0.125f;     // q pre-scaled by HD^-0.5
        unsigned u = f2bf(o0 * m) | (f2bf(o1 * m) << 16);
        unsigned short* dst = (isK ? kr : qr) + ((size_t)(b * 6 + hh) * NSEQ + n) * HD + 2 * pp;
        *(unsigned*)dst = u;
    }
    for (int e = t; e < 384; e += 256) {
        int hh = e >> 6, d = e & 63;
        vt[((size_t)(b * 6 + hh) * HD + d) * NSEQ + n] = row[768 + e];
    }
}

// ---------------------------------------------------------------- MFMA flash attention
// grid (24, 16); 256 thr = 4 waves; wave owns 16 q-rows; K-tile 64.
// All lens are multiples of 64 -> whole K-tiles, no in-kernel masking.
__global__ __launch_bounds__(256) void attn_mfma(
    const unsigned short* __restrict__ qr, const unsigned short* __restrict__ kr,
    const unsigned short* __restrict__ vt, unsigned short* __restrict__ o) {
    __shared__ unsigned short Ks[64][72];     // [key][d]
    __shared__ unsigned short Vs[64][72];     // [d][key]
    __shared__ unsigned short Pb[4][16][72];  // per-wave P [m][key]
    int bh = blockIdx.x;
    int b = bh / 6, hh = bh - b * 6;
    int q0 = blockIdx.y * 64;
    int len = c_lens[b];
    int t = threadIdx.x, wid = t >> 6, lane = t & 63;
    int lr = lane & 15, lq = lane >> 4;
    const unsigned short* Qp = qr + ((size_t)bh * NSEQ + q0 + wid * 16 + lr) * HD + lq * 8;
    bf16x8 qa0 = *(const bf16x8*)(Qp);
    bf16x8 qa1 = *(const bf16x8*)(Qp + 32);
    f32x4 oacc[4] = {};
    float m_r[4], l_r[4];
#pragma unroll
    for (int r = 0; r < 4; r++) { m_r[r] = -1e30f; l_r[r] = 0.f; }
    int srow = t >> 2, sc = (t & 3) * 8;
    const unsigned short* Kp = kr + (size_t)bh * NSEQ * HD + (size_t)srow * HD + sc;
    const unsigned short* Vp = vt + ((size_t)bh * HD + srow) * NSEQ + sc;
    bool evn = (lane & 1) == 0;
    int nt = len >> 6;
    for (int kt = 0; kt < nt; kt++) {
        int k0 = kt * 64;
        __syncthreads();   // prior PV reads done before restage
        *(uint4*)&Ks[srow][sc]      = *(const uint4*)(Kp + (size_t)k0 * HD);
        *(uint4*)&Ks[srow][sc + 32] = *(const uint4*)(Kp + (size_t)k0 * HD + 32);
        *(uint4*)&Vs[srow][sc]      = *(const uint4*)(Vp + k0);
        *(uint4*)&Vs[srow][sc + 32] = *(const uint4*)(Vp + k0 + 32);
        __syncthreads();
        // S = Q @ K^T : s[g] holds S[lq*4+r][g*16+lr]
        f32x4 s[4] = {};
#pragma unroll
        for (int g = 0; g < 4; g++) {
            bf16x8 kf0 = *(const bf16x8*)&Ks[g * 16 + lr][lq * 8];
            bf16x8 kf1 = *(const bf16x8*)&Ks[g * 16 + lr][32 + lq * 8];
            s[g] = __builtin_amdgcn_mfma_f32_16x16x32_bf16(qa0, kf0, s[g], 0, 0, 0);
            s[g] = __builtin_amdgcn_mfma_f32_16x16x32_bf16(qa1, kf1, s[g], 0, 0, 0);
        }
        // online softmax per row r (16-lane groups share a row)
        float alpha[4];
#pragma unroll
        for (int r = 0; r < 4; r++) {
            float mx = fmaxf(fmaxf(s[0][r], s[1][r]), fmaxf(s[2][r], s[3][r]));
            mx = fmaxf(mx, __shfl_xor(mx, 1));
            mx = fmaxf(mx, __shfl_xor(mx, 2));
            mx = fmaxf(mx, __shfl_xor(mx, 4));
            mx = fmaxf(mx, __shfl_xor(mx, 8));
            float mn = fmaxf(m_r[r], mx);
            alpha[r] = __expf(m_r[r] - mn);
            m_r[r] = mn;
            float sum = 0.f;
#pragma unroll
            for (int g = 0; g < 4; g++) {
                float p = __expf(s[g][r] - mn);
                s[g][r] = p;
                sum += p;
            }
            sum += __shfl_xor(sum, 1);
            sum += __shfl_xor(sum, 2);
            sum += __shfl_xor(sum, 4);
            sum += __shfl_xor(sum, 8);
            l_r[r] = l_r[r] * alpha[r] + sum;
        }
        // P -> bf16 -> per-wave LDS (pair lanes pack 2 cols into one dword)
#pragma unroll
        for (int g = 0; g < 4; g++) {
#pragma unroll
            for (int r = 0; r < 4; r++) {
                float p = s[g][r];
                float q = __shfl_xor(p, 1);
                float lo = evn ? p : q;
                float hi = evn ? q : p;
                unsigned u = f2bf(lo) | (f2bf(hi) << 16);
                if (evn == (r < 2))   // even lanes write rows r=0,1; odd rows r=2,3
                    *(unsigned*)&Pb[wid][lq * 4 + r][g * 16 + (lane & 14)] = u;
            }
        }
        // O = O*alpha + P @ V
#pragma unroll
        for (int g = 0; g < 4; g++)
#pragma unroll
            for (int r = 0; r < 4; r++) oacc[g][r] *= alpha[r];
        bf16x8 pa0 = *(const bf16x8*)&Pb[wid][lr][lq * 8];
        bf16x8 pa1 = *(const bf16x8*)&Pb[wid][lr][32 + lq * 8];
#pragma unroll
        for (int g = 0; g < 4; g++) {
            bf16x8 vf0 = *(const bf16x8*)&Vs[g * 16 + lr][lq * 8];
            bf16x8 vf1 = *(const bf16x8*)&Vs[g * 16 + lr][32 + lq * 8];
            oacc[g] = __builtin_amdgcn_mfma_f32_16x16x32_bf16(pa0, vf0, oacc[g], 0, 0, 0);
            oacc[g] = __builtin_amdgcn_mfma_f32_16x16x32_bf16(pa1, vf1, oacc[g], 0, 0, 0);
        }
    }
#pragma unroll
    for (int r = 0; r < 4; r++) {
        float inv = 1.f / l_r[r];
        int row = q0 + wid * 16 + lq * 4 + r;
#pragma unroll
        for (int g = 0; g < 4; g++)
            o[(size_t)(b * NSEQ + row) * EMBED + hh * HD + g * 16 + lr] =
                (unsigned short)f2bf(oacc[g][r] * inv);
    }
}

// ---------------------------------------------------------------- mask output
__global__ void mask_kernel(float* __restrict__ mout) {
    int idx = blockIdx.x * 256 + threadIdx.x;
    if (idx >= NROWS) return;
    int b = idx >> 10, n = idx & 1023;
    mout[idx] = (n >= c_lens[b]) ? 1.0f : 0.0f;
}

// ---------------------------------------------------------------- launch
extern "C" void kernel_launch(void* const* d_in, const int* in_sizes, int n_in,
                              void* d_out, int out_size, void* d_ws, size_t ws_size,
                              hipStream_t stream) {
    (void)in_sizes; (void)n_in; (void)out_size; (void)ws_size;
    const float* img0 = (const float*)d_in[0];
    const float* img1 = (const float*)d_in[1];
    const float* img2 = (const float*)d_in[2];
    const float* img3 = (const float*)d_in[3];
    const float* pe_ln_in_w  = (const float*)d_in[4];
    const float* pe_ln_in_b  = (const float*)d_in[5];
    const float* pe_w        = (const float*)d_in[6];
    const float* pe_ln_out_w = (const float*)d_in[7];
    const float* pe_ln_out_b = (const float*)d_in[8];
    const float* ln1_w  = (const float*)d_in[9];
    const float* ln1_b  = (const float*)d_in[10];
    const float* qkv_w  = (const float*)d_in[11];
    const float* qkv_b  = (const float*)d_in[12];
    const float* proj_w = (const float*)d_in[13];
    const float* proj_b = (const float*)d_in[14];
    const float* ln2_w  = (const float*)d_in[15];
    const float* ln2_b  = (const float*)d_in[16];
    const float* fc1_w  = (const float*)d_in[17];
    const float* fc1_b  = (const float*)d_in[18];
    const float* fc2_w  = (const float*)d_in[19];
    const float* fc2_b  = (const float*)d_in[20];
    const float* lnf_w  = (const float*)d_in[21];
    const float* lnf_b  = (const float*)d_in[22];

    char* ws = (char*)d_ws;
    // byte offsets (all 256-aligned)
    float*          x_f    = (float*)(ws + 0);                    //  6,291,456
    char*           R      = ws + 6291456;                        // 12,582,912 union region
    unsigned short* qkv_bf = (unsigned short*)R;                  //  9,437,184 (dead after rope)
    unsigned short* o_bf   = (unsigned short*)(R + 9437184);      //  3,145,728 (dead after proj)
    unsigned short* mlp_bf = (unsigned short*)R;                  // 12,582,912 (MLP phase only)
    unsigned short* h_bf   = (unsigned short*)(ws + 18874368);    //  3,145,728
    unsigned short* qr     = (unsigned short*)(ws + 22020096);    //  3,145,728
    unsigned short* kr     = (unsigned short*)(ws + 25165824);    //  3,145,728
    unsigned short* vt     = (unsigned short*)(ws + 28311552);    //  3,145,728
    float*          cosT   = (float*)(ws + 31457280);             //    524,288
    float*          sinT   = (float*)(ws + 31981568);             //    524,288
    float*          xin    = (float*)(ws + 32505856);             //  1,572,864
    unsigned short* xln_bf = (unsigned short*)(ws + 34078720);    //  1,048,576 ([4096][128], padded)
    unsigned short* pe_wt  = (unsigned short*)(ws + 35127296);    //     98,304 ([384][128])
    unsigned short* qkv_wt = (unsigned short*)(ws + 35225600);    // 10,616,832 ([12][1152][384])
    unsigned short* proj_wt= (unsigned short*)(ws + 45842432);    //  3,538,944 ([12][384][384])
    unsigned short* fc1_wt = (unsigned short*)(ws + 49381376);    // 14,155,776 ([12][1536][384])
    unsigned short* fc2_wt = (unsigned short*)(ws + 63537152);    // 14,155,776 ([12][384][1536])
    // total ~77.7 MB

    // ---- per-launch weight transpose+convert (deterministic) ----
    convT_kernel<<<dim3(4, 12, 1),   256, 0, stream>>>(pe_w,   pe_wt,   96,  EMBED, 128);
    convT_kernel<<<dim3(12, 36, 12), 256, 0, stream>>>(qkv_w,  qkv_wt,  384, 1152,  384);
    convT_kernel<<<dim3(12, 12, 12), 256, 0, stream>>>(proj_w, proj_wt, 384, 384,   384);
    convT_kernel<<<dim3(12, 48, 12), 256, 0, stream>>>(fc1_w,  fc1_wt,  384, 1536,  384);
    convT_kernel<<<dim3(48, 12, 12), 256, 0, stream>>>(fc2_w,  fc2_wt,  1536, 384,  1536);

    patchify_kernel<<<NROWS, 128, 0, stream>>>(img0, img1, img2, img3, xin, cosT, sinT);
    ln_kernel<PD, 128, true><<<NROWS / 4, 256, 0, stream>>>(xin, pe_ln_in_w, pe_ln_in_b, xln_bf);
    gemm_bf16<0><<<dim3(EMBED / 64, NROWS / 64), 256, 0, stream>>>(
        xln_bf, pe_wt, nullptr, nullptr, x_f, nullptr, NROWS, 128, EMBED);
    ln_kernel<EMBED, EMBED, false><<<NROWS / 4, 256, 0, stream>>>(x_f, pe_ln_out_w, pe_ln_out_b, x_f);

    for (int l = 0; l < 12; ++l) {
        ln_kernel<EMBED, EMBED, true><<<NROWS / 4, 256, 0, stream>>>(
            x_f, ln1_w + l * EMBED, ln1_b + l * EMBED, h_bf);
        gemm_bf16<9><<<dim3(1152 / 64, NROWS / 64), 256, 0, stream>>>(           // bias + bf16 out
            h_bf, qkv_wt + (size_t)l * 1152 * 384, qkv_b + (size_t)l * 1152, nullptr,
            nullptr, qkv_bf, NROWS, EMBED, 1152);
        rope_kernel<<<NROWS, 256, 0, stream>>>(qkv_bf, cosT, sinT, qr, kr, vt);
        attn_mfma<<<dim3(NB * NHEADS, NSEQ / 64), 256, 0, stream>>>(qr, kr, vt, o_bf);
        gemm_bf16<5><<<dim3(EMBED / 64, NROWS / 64), 256, 0, stream>>>(          // bias + residual
            o_bf, proj_wt + (size_t)l * 384 * 384, proj_b + (size_t)l * EMBED, x_f,
            x_f, nullptr, NROWS, EMBED, EMBED);
        ln_kernel<EMBED, EMBED, true><<<NROWS / 4, 256, 0, stream>>>(
            x_f, ln2_w + l * EMBED, ln2_b + l * EMBED, h_bf);
        gemm_bf16<11><<<dim3(1536 / 64, NROWS / 64), 256, 0, stream>>>(          // bias+gelu+bf16
            h_bf, fc1_wt + (size_t)l * 1536 * 384, fc1_b + (size_t)l * 1536, nullptr,
            nullptr, mlp_bf, NROWS, EMBED, 1536);
        gemm_bf16<5><<<dim3(EMBED / 64, NROWS / 64), 256, 0, stream>>>(
            mlp_bf, fc2_wt + (size_t)l * 384 * 1536, fc2_b + (size_t)l * EMBED, x_f,
            x_f, nullptr, NROWS, 1536, EMBED);
    }

    ln_kernel<EMBED, EMBED, false><<<NROWS / 4, 256, 0, stream>>>(x_f, lnf_w, lnf_b, (float*)d_out);
    mask_kernel<<<16, 256, 0, stream>>>((float*)d_out + (size_t)NROWS * EMBED);
}